// Round 8
// baseline (1115.062 us; speedup 1.0000x reference)
//
#include <hip/hip_runtime.h>

#define N_NODES 100000
#define N_EDGES 1600000
#define NB 782    // ceil(N_NODES/128) buckets of 128 dst-nodes
#define CAP 3072  // strip capacity per bucket (mean 2046, sigma 45 -> 22-sigma safe)
#define P1B 391   // pass1 blocks (4096 edges each)
#define CVB 625   // convert blocks
#define YP 72     // padded LDS row (bf16) for weights
#define AS 66     // agg stride (fp32), bucket1: 2*dl bank offset decorrelates octets
#define AS2 34    // agg stride (fp32), bucket2

typedef __attribute__((ext_vector_type(8))) short bhalf8;
typedef __attribute__((ext_vector_type(4))) float f32x4;

__device__ __forceinline__ unsigned short bf16r(float f) {
    unsigned u = __float_as_uint(f);
    unsigned r = (u >> 16) & 1;
    return (unsigned short)((u + 0x7fffu + r) >> 16);
}
__device__ __forceinline__ unsigned pk2(float a, float b) {
    return (unsigned)bf16r(a) | ((unsigned)bf16r(b) << 16);
}
__device__ __forceinline__ float bl(unsigned u) { return __uint_as_float(u << 16); }
__device__ __forceinline__ float bh(unsigned u) { return __uint_as_float(u & 0xffff0000u); }

// ---------------- prep: pass1 (blocks 0..P1B-1) || convert (blocks P1B..) ------
__global__ __launch_bounds__(256) void prep(const float4* __restrict__ X4,
                                            uint2* __restrict__ Xb,
                                            const int* __restrict__ src,
                                            const int* __restrict__ dst,
                                            int* __restrict__ gcur,
                                            unsigned* __restrict__ ebuf) {
    __shared__ int h[NB];
    __shared__ int cur[NB];
    int t = threadIdx.x;
    if (blockIdx.x < P1B) {
        for (int b = t; b < NB; b += 256) h[b] = 0;
        __syncthreads();
        int e0 = blockIdx.x * 4096 + t;
        unsigned pk[16]; int bk[16];
#pragma unroll
        for (int i = 0; i < 16; i++) {
            int e = e0 + i * 256;
            if (e < N_EDGES) {
                int s = src[e], d = dst[e];
                bk[i] = d >> 7;
                pk[i] = ((unsigned)s << 7) | (unsigned)(d & 127);
                atomicAdd(&h[bk[i]], 1);
            } else bk[i] = -1;
        }
        __syncthreads();
        for (int b = t; b < NB; b += 256)
            cur[b] = h[b] ? (b * CAP + atomicAdd(&gcur[b], h[b])) : 0;
        __syncthreads();
#pragma unroll
        for (int i = 0; i < 16; i++)
            if (bk[i] >= 0) {
                int r = atomicAdd(&cur[bk[i]], 1);
                ebuf[r] = pk[i];
            }
    } else {
        for (int i = (blockIdx.x - P1B) * 256 + t; i < N_NODES * 16; i += CVB * 256) {
            float4 v = X4[i];
            uint2 o; o.x = pk2(v.x, v.y); o.y = pk2(v.z, v.w);
            Xb[i] = o;
        }
    }
}

// ---------------- bucket1: edge-parallel LDS-atomic aggregate + MFMA gemm ------
// Phase A: each octet takes one edge, LDS ds_add_f32 into agg[dl][ch] (fp32).
// Phase B: waves 0..7, one 16-node tile each: Zb = relu(agg@W1+b1)@W2.
__global__ __launch_bounds__(1024) void bucket1(
    const unsigned* __restrict__ ebuf, const int* __restrict__ gcur,
    const uint4* __restrict__ Xb4,
    const float* __restrict__ W1, const float* __restrict__ b1,
    const float* __restrict__ W2,
    unsigned short* __restrict__ Zb) {
    __shared__ float agg[128 * AS];             // 33.8 KB
    __shared__ unsigned short sW1t[64 * YP];    // W1^T [h][k]
    __shared__ unsigned short sW2t[32 * YP];    // W2^T [oc][h]
    int b = blockIdx.x, t = threadIdx.x;
    int base = b * CAP, cnt = gcur[b];
    for (int i = t; i < 128 * AS; i += 1024) agg[i] = 0.f;
    for (int i = t; i < 64 * 64; i += 1024) {
        int k = i >> 6, hc = i & 63;
        sW1t[hc * YP + k] = bf16r(W1[k * 64 + hc]);
    }
    for (int i = t; i < 64 * 32; i += 1024) {
        int k = i >> 5, oc = i & 31;
        sW2t[oc * YP + k] = bf16r(W2[k * 32 + oc]);
    }
    __syncthreads();

    int il = t & 7;
    int i = t >> 3;
    for (; i + 128 < cnt; i += 256) {  // 2 edges in flight per lane
        unsigned va = ebuf[base + i], vb = ebuf[base + i + 128];
        uint4 xa = Xb4[(va >> 7) * 8 + il];
        uint4 xb = Xb4[(vb >> 7) * 8 + il];
        float* ra = &agg[(int)(va & 127) * AS + il * 8];
        float* rb = &agg[(int)(vb & 127) * AS + il * 8];
        atomicAdd(ra + 0, bl(xa.x)); atomicAdd(ra + 1, bh(xa.x));
        atomicAdd(ra + 2, bl(xa.y)); atomicAdd(ra + 3, bh(xa.y));
        atomicAdd(ra + 4, bl(xa.z)); atomicAdd(ra + 5, bh(xa.z));
        atomicAdd(ra + 6, bl(xa.w)); atomicAdd(ra + 7, bh(xa.w));
        atomicAdd(rb + 0, bl(xb.x)); atomicAdd(rb + 1, bh(xb.x));
        atomicAdd(rb + 2, bl(xb.y)); atomicAdd(rb + 3, bh(xb.y));
        atomicAdd(rb + 4, bl(xb.z)); atomicAdd(rb + 5, bh(xb.z));
        atomicAdd(rb + 6, bl(xb.w)); atomicAdd(rb + 7, bh(xb.w));
    }
    for (; i < cnt; i += 128) {
        unsigned va = ebuf[base + i];
        uint4 xa = Xb4[(va >> 7) * 8 + il];
        float* ra = &agg[(int)(va & 127) * AS + il * 8];
        atomicAdd(ra + 0, bl(xa.x)); atomicAdd(ra + 1, bh(xa.x));
        atomicAdd(ra + 2, bl(xa.y)); atomicAdd(ra + 3, bh(xa.y));
        atomicAdd(ra + 4, bl(xa.z)); atomicAdd(ra + 5, bh(xa.z));
        atomicAdd(ra + 6, bl(xa.w)); atomicAdd(ra + 7, bh(xa.w));
    }
    __syncthreads();

    int lane = t & 63, wid = t >> 6;
    if (wid < 8) {
        int m = lane & 15, quad = lane >> 4;
        int nl = wid * 16 + m;
        int node = b * 128 + nl;
        float* ar = &agg[nl * AS];
        // B fragments (agg row, fp32 -> bf16)
        union { bhalf8 v; unsigned u[4]; } B0, B1;
#pragma unroll
        for (int k = 0; k < 4; k++) {
            B0.u[k] = pk2(ar[quad * 8 + 2 * k], ar[quad * 8 + 2 * k + 1]);
            B1.u[k] = pk2(ar[32 + quad * 8 + 2 * k], ar[32 + quad * 8 + 2 * k + 1]);
        }
        unsigned short* ys = (unsigned short*)ar;  // reuse own row as y scratch
#pragma unroll
        for (int tile = 0; tile < 4; tile++) {
            f32x4 a;
#pragma unroll
            for (int r = 0; r < 4; r++) a[r] = b1[tile * 16 + quad * 4 + r];
            bhalf8 A0 = *(const bhalf8*)&sW1t[(tile * 16 + m) * YP + quad * 8];
            bhalf8 A1 = *(const bhalf8*)&sW1t[(tile * 16 + m) * YP + 32 + quad * 8];
            a = __builtin_amdgcn_mfma_f32_16x16x32_bf16(A0, B0.v, a, 0, 0, 0);
            a = __builtin_amdgcn_mfma_f32_16x16x32_bf16(A1, B1.v, a, 0, 0, 0);
            float y0 = a[0] > 0.f ? a[0] : 0.f, y1 = a[1] > 0.f ? a[1] : 0.f;
            float y2 = a[2] > 0.f ? a[2] : 0.f, y3 = a[3] > 0.f ? a[3] : 0.f;
            uint2 o; o.x = pk2(y0, y1); o.y = pk2(y2, y3);
            *(uint2*)&ys[tile * 16 + quad * 4] = o;  // y[node][h], shorts
        }
        __asm__ __volatile__("s_waitcnt lgkmcnt(0)" ::: "memory");
        union { bhalf8 v; uint2 u2[2]; } Y0, Y1;
        Y0.u2[0] = *(uint2*)&ys[quad * 8];
        Y0.u2[1] = *(uint2*)&ys[quad * 8 + 4];
        Y1.u2[0] = *(uint2*)&ys[32 + quad * 8];
        Y1.u2[1] = *(uint2*)&ys[32 + quad * 8 + 4];
#pragma unroll
        for (int tile = 0; tile < 2; tile++) {
            bhalf8 A0 = *(const bhalf8*)&sW2t[(tile * 16 + m) * YP + quad * 8];
            bhalf8 A1 = *(const bhalf8*)&sW2t[(tile * 16 + m) * YP + 32 + quad * 8];
            f32x4 z = {0.f, 0.f, 0.f, 0.f};
            z = __builtin_amdgcn_mfma_f32_16x16x32_bf16(A0, Y0.v, z, 0, 0, 0);
            z = __builtin_amdgcn_mfma_f32_16x16x32_bf16(A1, Y1.v, z, 0, 0, 0);
            if (node < N_NODES) {
                uint2 o; o.x = pk2(z[0], z[1]); o.y = pk2(z[2], z[3]);
                *(uint2*)&Zb[(size_t)node * 32 + tile * 16 + quad * 4] = o;
            }
        }
    }
}

// ---------------- bucket2: edge-parallel LDS-atomic aggregate of Zb + b2 -------
__global__ __launch_bounds__(1024) void bucket2(
    const unsigned* __restrict__ ebuf, const int* __restrict__ gcur,
    const uint4* __restrict__ Zb4,
    const float* __restrict__ b2, float4* __restrict__ out4) {
    __shared__ float agg[128 * AS2];  // 17.4 KB
    int b = blockIdx.x, t = threadIdx.x;
    int base = b * CAP, cnt = gcur[b];
    for (int i = t; i < 128 * AS2; i += 1024) agg[i] = 0.f;
    __syncthreads();
    int il = t & 3;
    int i = t >> 2;
    for (; i + 256 < cnt; i += 512) {
        unsigned va = ebuf[base + i], vb = ebuf[base + i + 256];
        uint4 za = Zb4[(va >> 7) * 4 + il];
        uint4 zb = Zb4[(vb >> 7) * 4 + il];
        float* ra = &agg[(int)(va & 127) * AS2 + il * 8];
        float* rb = &agg[(int)(vb & 127) * AS2 + il * 8];
        atomicAdd(ra + 0, bl(za.x)); atomicAdd(ra + 1, bh(za.x));
        atomicAdd(ra + 2, bl(za.y)); atomicAdd(ra + 3, bh(za.y));
        atomicAdd(ra + 4, bl(za.z)); atomicAdd(ra + 5, bh(za.z));
        atomicAdd(ra + 6, bl(za.w)); atomicAdd(ra + 7, bh(za.w));
        atomicAdd(rb + 0, bl(zb.x)); atomicAdd(rb + 1, bh(zb.x));
        atomicAdd(rb + 2, bl(zb.y)); atomicAdd(rb + 3, bh(zb.y));
        atomicAdd(rb + 4, bl(zb.z)); atomicAdd(rb + 5, bh(zb.z));
        atomicAdd(rb + 6, bl(zb.w)); atomicAdd(rb + 7, bh(zb.w));
    }
    for (; i < cnt; i += 256) {
        unsigned va = ebuf[base + i];
        uint4 za = Zb4[(va >> 7) * 4 + il];
        float* ra = &agg[(int)(va & 127) * AS2 + il * 8];
        atomicAdd(ra + 0, bl(za.x)); atomicAdd(ra + 1, bh(za.x));
        atomicAdd(ra + 2, bl(za.y)); atomicAdd(ra + 3, bh(za.y));
        atomicAdd(ra + 4, bl(za.z)); atomicAdd(ra + 5, bh(za.z));
        atomicAdd(ra + 6, bl(za.w)); atomicAdd(ra + 7, bh(za.w));
    }
    __syncthreads();
    // writeout: t -> (node_local, float4-chunk)
    int nl = t >> 3, q = t & 7;
    int node = b * 128 + nl;
    if (node < N_NODES) {
        float* ar = &agg[nl * AS2 + q * 4];
        float4 bb = ((const float4*)b2)[q];
        float4 o;
        o.x = ar[0] + bb.x; o.y = ar[1] + bb.y;
        o.z = ar[2] + bb.z; o.w = ar[3] + bb.w;
        out4[node * 8 + q] = o;
    }
}

extern "C" void kernel_launch(void* const* d_in, const int* in_sizes, int n_in,
                              void* d_out, int out_size, void* d_ws, size_t ws_size,
                              hipStream_t stream) {
    const float* features = (const float*)d_in[0];
    const int*   src      = (const int*)d_in[1];
    const int*   dst      = (const int*)d_in[2];
    const float* W1       = (const float*)d_in[3];
    const float* b1       = (const float*)d_in[4];
    const float* W2       = (const float*)d_in[5];
    const float* b2       = (const float*)d_in[6];

    char* p = (char*)d_ws;
    int* gcur = (int*)p;           p += 1024 * 4;
    unsigned* ebuf = (unsigned*)p; p += (size_t)NB * CAP * 4;
    uint2* Xb = (uint2*)p;         p += (size_t)N_NODES * 64 * 2;
    unsigned short* Zb = (unsigned short*)p; p += (size_t)N_NODES * 32 * 2;

    hipMemsetAsync(gcur, 0, NB * sizeof(int), stream);
    prep<<<P1B + CVB, 256, 0, stream>>>((const float4*)features, Xb, src, dst, gcur, ebuf);
    bucket1<<<NB, 1024, 0, stream>>>(ebuf, gcur, (const uint4*)Xb, W1, b1, W2, Zb);
    bucket2<<<NB, 1024, 0, stream>>>(ebuf, gcur, (const uint4*)Zb, b2, (float4*)d_out);
}

// Round 9
// 202.482 us; speedup vs baseline: 5.5070x; 5.5070x over previous
//
#include <hip/hip_runtime.h>

#define N_NODES 100000
#define N_EDGES 1600000
#define NB 782    // ceil(N_NODES/128) buckets of 128 dst-nodes
#define CAP 3072  // strip capacity per bucket (mean 2046, sigma 45 -> 22-sigma safe)
#define YP 72     // padded LDS row (bf16) for weights
#define AP 72     // padded LDS agg row (bf16)

typedef __attribute__((ext_vector_type(8))) short bhalf8;
typedef __attribute__((ext_vector_type(4))) float f32x4;

__device__ __forceinline__ unsigned short bf16r(float f) {
    unsigned u = __float_as_uint(f);
    unsigned r = (u >> 16) & 1;
    return (unsigned short)((u + 0x7fffu + r) >> 16);
}
__device__ __forceinline__ unsigned pk2(float a, float b) {
    return (unsigned)bf16r(a) | ((unsigned)bf16r(b) << 16);
}
__device__ __forceinline__ float bl(unsigned u) { return __uint_as_float(u << 16); }
__device__ __forceinline__ float bh(unsigned u) { return __uint_as_float(u & 0xffff0000u); }

// ---------------- prepass: features -> bf16, init strip cursors ----------------
__global__ void convert_zero(const float4* __restrict__ X4, uint2* __restrict__ Xb,
                             int* __restrict__ gcur) {
    int i = blockIdx.x * 256 + threadIdx.x;
    if (i < N_NODES * 16) {
        float4 v = X4[i];
        uint2 o; o.x = pk2(v.x, v.y); o.y = pk2(v.z, v.w);
        Xb[i] = o;
    }
    if (i < NB) gcur[i] = i * CAP;
}

// ---------------- pass1: scatter packed (src<<7|dstlocal) into bucket strips ----
__global__ __launch_bounds__(256) void pass1(const int* __restrict__ src,
                                             const int* __restrict__ dst,
                                             int* __restrict__ gcur,
                                             unsigned* __restrict__ ebuf) {
    __shared__ int h[NB];
    __shared__ int cur[NB];
    int t = threadIdx.x;
    for (int b = t; b < NB; b += 256) h[b] = 0;
    __syncthreads();
    int e0 = blockIdx.x * 4096 + t;
    unsigned pk[16]; int bk[16];
#pragma unroll
    for (int i = 0; i < 16; i++) {
        int e = e0 + i * 256;
        if (e < N_EDGES) {
            int s = src[e], d = dst[e];
            bk[i] = d >> 7;
            pk[i] = ((unsigned)s << 7) | (unsigned)(d & 127);
            atomicAdd(&h[bk[i]], 1);
        } else bk[i] = -1;
    }
    __syncthreads();
    for (int b = t; b < NB; b += 256)
        cur[b] = h[b] ? atomicAdd(&gcur[b], h[b]) : 0;
    __syncthreads();
#pragma unroll
    for (int i = 0; i < 16; i++)
        if (bk[i] >= 0) {
            int r = atomicAdd(&cur[bk[i]], 1);
            ebuf[r] = pk[i];
        }
}

// ---------------- bucket1: sort + gather + MFMA gemm, 512 thr, 3 blocks/CU -----
// Phases: hist -> wave-scan -> off/deg -> LDS rank-sort (stg) -> csr write ->
// per-wave 16-node shfl-gather into bf16 agg tile -> MFMA Zb=relu(agg@W1+b1)@W2.
__global__ __launch_bounds__(512) void bucket1(
    const unsigned* __restrict__ ebuf, const int* __restrict__ gcur,
    const uint4* __restrict__ Xb4,
    const float* __restrict__ W1, const float* __restrict__ b1,
    const float* __restrict__ W2,
    int* __restrict__ off, int* __restrict__ deg, int* __restrict__ csr,
    unsigned short* __restrict__ Zb) {
    __shared__ int hh[128], nodeoff[129], scv[128];
    __shared__ unsigned short sW1t[64 * YP];   // 9216 B  W1^T [h][k]
    __shared__ unsigned short sW2t[32 * YP];   // 4608 B  W2^T [oc][h]
    __shared__ unsigned short agg[128 * AP];   // 18432 B agg tile [nl][ch] (bf16)
    __shared__ int stg[CAP];                   // 12288 B sorted src list

    int b = blockIdx.x, t = threadIdx.x;
    int base = b * CAP, cnt = gcur[b] - base;
    int lane = t & 63, wid = t >> 6;
    if (t < 128) hh[t] = 0;
    for (int i = t; i < 64 * 64; i += 512) {
        int k = i >> 6, hc = i & 63;
        sW1t[hc * YP + k] = bf16r(W1[k * 64 + hc]);
    }
    for (int i = t; i < 64 * 32; i += 512) {
        int k = i >> 5, oc = i & 31;
        sW2t[oc * YP + k] = bf16r(W2[k * 32 + oc]);
    }
    __syncthreads();
    for (int i = t; i < cnt; i += 512) atomicAdd(&hh[ebuf[base + i] & 127], 1);
    __syncthreads();
    if (wid == 0) {  // wave-parallel exclusive scan of 128 (2 elems/lane)
        int v0 = hh[2 * lane], v1 = hh[2 * lane + 1];
        int ps = v0 + v1, s = ps;
        for (int o = 1; o < 64; o <<= 1) {
            int u = __shfl_up(s, o);
            if (lane >= o) s += u;
        }
        int excl = s - ps;
        nodeoff[2 * lane] = excl;
        nodeoff[2 * lane + 1] = excl + v0;
        if (lane == 63) nodeoff[128] = s;
    }
    __syncthreads();
    if (t < 128) {
        int n = b * 128 + t;
        if (n < N_NODES) { off[n] = base + nodeoff[t]; deg[n] = hh[t]; }
        scv[t] = nodeoff[t];
    }
    __syncthreads();
    for (int i = t; i < cnt; i += 512) {
        unsigned v = ebuf[base + i];
        int r = atomicAdd(&scv[v & 127], 1);
        stg[r] = (int)(v >> 7);
    }
    __syncthreads();
    for (int i = t; i < cnt; i += 512) csr[base + i] = stg[i];

    // ---- gather: 8 waves x 16 consecutive nodes each ----
    int il = lane & 7, g = lane >> 3;
#pragma unroll 1
    for (int nl = wid * 16; nl < wid * 16 + 16; nl++) {
        int s0 = nodeoff[nl], d = hh[nl];
        float a0 = 0.f, a1 = 0.f, a2 = 0.f, a3 = 0.f;
        float a4 = 0.f, a5 = 0.f, a6 = 0.f, a7 = 0.f;
        int j = g;
        for (; j + 8 < d; j += 16) {
            int sa = stg[s0 + j], sb = stg[s0 + j + 8];
            uint4 va = Xb4[sa * 8 + il], vb = Xb4[sb * 8 + il];
            a0 += bl(va.x) + bl(vb.x); a1 += bh(va.x) + bh(vb.x);
            a2 += bl(va.y) + bl(vb.y); a3 += bh(va.y) + bh(vb.y);
            a4 += bl(va.z) + bl(vb.z); a5 += bh(va.z) + bh(vb.z);
            a6 += bl(va.w) + bl(vb.w); a7 += bh(va.w) + bh(vb.w);
        }
        if (j < d) {
            int sa = stg[s0 + j];
            uint4 va = Xb4[sa * 8 + il];
            a0 += bl(va.x); a1 += bh(va.x); a2 += bl(va.y); a3 += bh(va.y);
            a4 += bl(va.z); a5 += bh(va.z); a6 += bl(va.w); a7 += bh(va.w);
        }
#pragma unroll
        for (int m = 8; m < 64; m <<= 1) {
            a0 += __shfl_xor(a0, m); a1 += __shfl_xor(a1, m);
            a2 += __shfl_xor(a2, m); a3 += __shfl_xor(a3, m);
            a4 += __shfl_xor(a4, m); a5 += __shfl_xor(a5, m);
            a6 += __shfl_xor(a6, m); a7 += __shfl_xor(a7, m);
        }
        if (g == 0) {
            uint4 o;
            o.x = pk2(a0, a1); o.y = pk2(a2, a3);
            o.z = pk2(a4, a5); o.w = pk2(a6, a7);
            *(uint4*)&agg[nl * AP + il * 8] = o;  // nl*144 + il*16 B, 16B aligned
        }
    }
    __syncthreads();

    // ---- MFMA: 8 waves x one 16-node tile; y overlays the wave's own agg rows --
    {
        int m = lane & 15, quad = lane >> 4;
        int nl = wid * 16 + m;
        int node = b * 128 + nl;
        bhalf8 Bc0 = *(const bhalf8*)&agg[nl * AP + quad * 8];
        bhalf8 Bc1 = *(const bhalf8*)&agg[nl * AP + 32 + quad * 8];
        unsigned short* ys = &agg[nl * AP];  // reuse own row as y scratch
#pragma unroll
        for (int tile = 0; tile < 4; tile++) {
            f32x4 a;
#pragma unroll
            for (int r = 0; r < 4; r++) a[r] = b1[tile * 16 + quad * 4 + r];
            bhalf8 A0 = *(const bhalf8*)&sW1t[(tile * 16 + m) * YP + quad * 8];
            bhalf8 A1 = *(const bhalf8*)&sW1t[(tile * 16 + m) * YP + 32 + quad * 8];
            a = __builtin_amdgcn_mfma_f32_16x16x32_bf16(A0, Bc0, a, 0, 0, 0);
            a = __builtin_amdgcn_mfma_f32_16x16x32_bf16(A1, Bc1, a, 0, 0, 0);
            float y0 = a[0] > 0.f ? a[0] : 0.f, y1 = a[1] > 0.f ? a[1] : 0.f;
            float y2 = a[2] > 0.f ? a[2] : 0.f, y3 = a[3] > 0.f ? a[3] : 0.f;
            uint2 o; o.x = pk2(y0, y1); o.y = pk2(y2, y3);
            *(uint2*)&ys[tile * 16 + quad * 4] = o;
        }
        __asm__ __volatile__("s_waitcnt lgkmcnt(0)" ::: "memory");
        union { bhalf8 v; uint2 u2[2]; } Y0, Y1;
        Y0.u2[0] = *(uint2*)&ys[quad * 8];
        Y0.u2[1] = *(uint2*)&ys[quad * 8 + 4];
        Y1.u2[0] = *(uint2*)&ys[32 + quad * 8];
        Y1.u2[1] = *(uint2*)&ys[32 + quad * 8 + 4];
#pragma unroll
        for (int tile = 0; tile < 2; tile++) {
            bhalf8 A0 = *(const bhalf8*)&sW2t[(tile * 16 + m) * YP + quad * 8];
            bhalf8 A1 = *(const bhalf8*)&sW2t[(tile * 16 + m) * YP + 32 + quad * 8];
            f32x4 z = {0.f, 0.f, 0.f, 0.f};
            z = __builtin_amdgcn_mfma_f32_16x16x32_bf16(A0, Y0.v, z, 0, 0, 0);
            z = __builtin_amdgcn_mfma_f32_16x16x32_bf16(A1, Y1.v, z, 0, 0, 0);
            if (node < N_NODES) {
                uint2 o; o.x = pk2(z[0], z[1]); o.y = pk2(z[2], z[3]);
                *(uint2*)&Zb[(size_t)node * 32 + tile * 16 + quad * 4] = o;
            }
        }
    }
}

// ---------------- gather 2: out[n] = sum Zb[src] + b2 (fp32 out) ----------------
__global__ __launch_bounds__(256) void gather2(
    const uint2* __restrict__ Zb2, const int* __restrict__ off,
    const int* __restrict__ deg, const int* __restrict__ csr,
    const float* __restrict__ b2, float4* __restrict__ out4) {
    int t = threadIdx.x, lane = t & 63, wid = t >> 6;
    int il = lane & 7, g = lane >> 3;
    float4 bb = ((const float4*)b2)[il];
    int w0 = blockIdx.x * 4 + wid, stride = gridDim.x * 4;
    for (int n = w0; n < N_NODES; n += stride) {
        int s0 = off[n], d = deg[n];
        float a0 = 0.f, a1 = 0.f, a2 = 0.f, a3 = 0.f;
        int j = g;
        for (; j + 8 < d; j += 16) {
            int sa = csr[s0 + j], sb = csr[s0 + j + 8];
            uint2 va = Zb2[sa * 8 + il], vb = Zb2[sb * 8 + il];
            a0 += bl(va.x) + bl(vb.x); a1 += bh(va.x) + bh(vb.x);
            a2 += bl(va.y) + bl(vb.y); a3 += bh(va.y) + bh(vb.y);
        }
        if (j < d) {
            int sa = csr[s0 + j];
            uint2 va = Zb2[sa * 8 + il];
            a0 += bl(va.x); a1 += bh(va.x); a2 += bl(va.y); a3 += bh(va.y);
        }
#pragma unroll
        for (int m = 8; m < 64; m <<= 1) {
            a0 += __shfl_xor(a0, m); a1 += __shfl_xor(a1, m);
            a2 += __shfl_xor(a2, m); a3 += __shfl_xor(a3, m);
        }
        if (g == 0) {
            float4 o;
            o.x = a0 + bb.x; o.y = a1 + bb.y; o.z = a2 + bb.z; o.w = a3 + bb.w;
            out4[n * 8 + il] = o;
        }
    }
}

extern "C" void kernel_launch(void* const* d_in, const int* in_sizes, int n_in,
                              void* d_out, int out_size, void* d_ws, size_t ws_size,
                              hipStream_t stream) {
    const float* features = (const float*)d_in[0];
    const int*   src      = (const int*)d_in[1];
    const int*   dst      = (const int*)d_in[2];
    const float* W1       = (const float*)d_in[3];
    const float* b1       = (const float*)d_in[4];
    const float* W2       = (const float*)d_in[5];
    const float* b2       = (const float*)d_in[6];

    char* p = (char*)d_ws;
    int* gcur = (int*)p;           p += 1024 * 4;
    int* off  = (int*)p;           p += ((size_t)N_NODES * 4 + 255) / 256 * 256;
    int* deg  = (int*)p;           p += ((size_t)N_NODES * 4 + 255) / 256 * 256;
    unsigned* ebuf = (unsigned*)p; p += (size_t)NB * CAP * 4;
    int* csr  = (int*)p;           p += (size_t)NB * CAP * 4;
    uint2* Xb = (uint2*)p;         p += (size_t)N_NODES * 64 * 2;
    unsigned short* Zb = (unsigned short*)p; p += (size_t)N_NODES * 32 * 2;

    convert_zero<<<(N_NODES * 16 + 255) / 256, 256, 0, stream>>>((const float4*)features, Xb, gcur);
    pass1<<<(N_EDGES + 4095) / 4096, 256, 0, stream>>>(src, dst, gcur, ebuf);
    bucket1<<<NB, 512, 0, stream>>>(ebuf, gcur, (const uint4*)Xb, W1, b1, W2,
                                    off, deg, csr, Zb);
    gather2<<<2048, 256, 0, stream>>>((const uint2*)Zb, off, deg, csr, b2, (float4*)d_out);
}